// Round 3
// baseline (488.016 us; speedup 1.0000x reference)
//
#include <hip/hip_runtime.h>
#include <stdint.h>

typedef unsigned short ushort_t;
typedef short bf16x8 __attribute__((ext_vector_type(8)));
typedef float f32x4 __attribute__((ext_vector_type(4)));
typedef float f32x4v __attribute__((ext_vector_type(4)));

// ---------- helpers ----------
__device__ __forceinline__ ushort_t f2bf(float f) {
  unsigned int u = __builtin_bit_cast(unsigned int, f);
  u += 0x7fffu + ((u >> 16) & 1u);
  return (ushort_t)(u >> 16);
}
__device__ __forceinline__ float bf2f(ushort_t h) {
  unsigned int u = ((unsigned int)h) << 16;
  return __builtin_bit_cast(float, u);
}
__device__ __forceinline__ void load_lds16(const void* g, void* l) {
  __builtin_amdgcn_global_load_lds(
      (const __attribute__((address_space(1))) void*)g,
      (__attribute__((address_space(3))) void*)l, 16, 0, 0);
}

// ---------- x fp32 -> bf16 ----------
__global__ __launch_bounds__(256) void cvt_x_kernel(const float* __restrict__ x,
                                                    ushort_t* __restrict__ xb) {
  int i = blockIdx.x * 256 + threadIdx.x;  // each thread: 8 elems
  const f32x4v* xv = (const f32x4v*)x;
  f32x4v a = xv[2 * i], b = xv[2 * i + 1];
  bf16x8 o;
  o[0] = (short)f2bf(a[0]); o[1] = (short)f2bf(a[1]);
  o[2] = (short)f2bf(a[2]); o[3] = (short)f2bf(a[3]);
  o[4] = (short)f2bf(b[0]); o[5] = (short)f2bf(b[1]);
  o[6] = (short)f2bf(b[2]); o[7] = (short)f2bf(b[3]);
  ((bf16x8*)xb)[i] = o;
}

// ---------- weight fp32 [R][C] -> bf16 transposed [C][R] ----------
__global__ __launch_bounds__(256) void tr_cvt_kernel(const float* __restrict__ src,
                                                     ushort_t* __restrict__ dst,
                                                     int R, int C) {
  __shared__ float tile[64][65];
  int r0 = blockIdx.y * 64, c0 = blockIdx.x * 64;
  int t = threadIdx.x;
#pragma unroll
  for (int i = 0; i < 16; i++) {
    int idx = t + i * 256;
    int r = idx >> 6, c = idx & 63;
    tile[r][c] = src[(size_t)(r0 + r) * C + c0 + c];
  }
  __syncthreads();
#pragma unroll
  for (int i = 0; i < 16; i++) {
    int idx = t + i * 256;
    int cr = idx >> 6, cc = idx & 63;
    dst[(size_t)(c0 + cr) * R + r0 + cc] = f2bf(tile[cc][cr]);
  }
}

// ---------- RoPE in-place on C1 (Q cols 0..4095, K cols 4096..5119) ----------
__global__ __launch_bounds__(256) void rope_kernel(ushort_t* __restrict__ C1,
                                                   const float* __restrict__ cosb,
                                                   const float* __restrict__ sinb) {
  int idx = blockIdx.x * 256 + threadIdx.x;  // 2048 * 640
  int s = idx / 640;
  int col0 = (idx % 640) * 8;
  int i0 = (col0 & 127) >> 1;
  ushort_t* p = C1 + (size_t)s * 6144 + col0;
  bf16x8 v = *(const bf16x8*)p;
  bf16x8 o;
  const float* cr = cosb + s * 64 + i0;
  const float* sr = sinb + s * 64 + i0;
#pragma unroll
  for (int j = 0; j < 4; j++) {
    float tr = bf2f((ushort_t)v[2 * j]);
    float ti = bf2f((ushort_t)v[2 * j + 1]);
    float c = cr[j], sn = sr[j];
    o[2 * j] = (short)f2bf(tr * c - ti * sn);
    o[2 * j + 1] = (short)f2bf(tr * sn + ti * c);
  }
  *(bf16x8*)p = o;
}

// ---------- V part of C1 -> VT [1024][2048] (row = hk*128+d, col = s) ----------
__global__ __launch_bounds__(256) void trv_kernel(const ushort_t* __restrict__ C1,
                                                  ushort_t* __restrict__ VT) {
  __shared__ ushort_t tile[64][65];
  int c0 = blockIdx.x * 64;  // within 1024
  int r0 = blockIdx.y * 64;  // within 2048
  int t = threadIdx.x;
#pragma unroll
  for (int i = 0; i < 16; i++) {
    int idx = t + i * 256;
    int r = idx >> 6, c = idx & 63;
    tile[r][c] = C1[(size_t)(r0 + r) * 6144 + 5120 + c0 + c];
  }
  __syncthreads();
#pragma unroll
  for (int i = 0; i < 16; i++) {
    int idx = t + i * 256;
    int cr = idx >> 6, cc = idx & 63;
    VT[(size_t)(c0 + cr) * 2048 + r0 + cc] = tile[cc][cr];
  }
}

// ---------- GEMM: C[M][ldc] = A[M][K] * BT[N][K]^T  (m97 structure) ----------
template <typename OutT>
__global__ __launch_bounds__(256) void gemm128_kernel(const ushort_t* __restrict__ A,
                                                      const ushort_t* __restrict__ BT,
                                                      OutT* __restrict__ C,
                                                      int M, int N, int K, int ldc) {
  __shared__ ushort_t As[128 * 32];
  __shared__ ushort_t Bs[128 * 32];
  int brow = blockIdx.y * 128, bcol = blockIdx.x * 128;
  int tid = threadIdx.x, w = tid >> 6, lane = tid & 63;
  int wr = w >> 1, wc = w & 1;
  int lr = lane & 15, lk = lane >> 4;
  f32x4 acc[4][4] = {};

  int srow = lane >> 2;
  int scol = (lane & 3) * 8;
  const ushort_t* Ab = A + (size_t)brow * K + scol;
  const ushort_t* Bb = BT + (size_t)bcol * K + scol;

  for (int kt = 0; kt < K; kt += 32) {
#pragma unroll
    for (int i = 0; i < 2; i++) {
      int seg = w * 2 + i;
      int row = seg * 16 + srow;
      load_lds16(Ab + (size_t)row * K + kt, (char*)As + seg * 1024);
      load_lds16(Bb + (size_t)row * K + kt, (char*)Bs + seg * 1024);
    }
    __syncthreads();
    bf16x8 af[4], bfr[4];
#pragma unroll
    for (int m = 0; m < 4; m++)
      af[m] = *(const bf16x8*)&As[(wr * 64 + m * 16 + lr) * 32 + lk * 8];
#pragma unroll
    for (int n = 0; n < 4; n++)
      bfr[n] = *(const bf16x8*)&Bs[(wc * 64 + n * 16 + lr) * 32 + lk * 8];
#pragma unroll
    for (int m = 0; m < 4; m++)
#pragma unroll
      for (int n = 0; n < 4; n++)
        acc[m][n] = __builtin_amdgcn_mfma_f32_16x16x32_bf16(af[m], bfr[n], acc[m][n], 0, 0, 0);
    __syncthreads();
  }
#pragma unroll
  for (int m = 0; m < 4; m++)
#pragma unroll
    for (int n = 0; n < 4; n++) {
      int row = brow + wr * 64 + m * 16 + lk * 4;
      int col = bcol + wc * 64 + n * 16 + lr;
#pragma unroll
      for (int j = 0; j < 4; j++) {
        float v = acc[m][n][j];
        if constexpr (sizeof(OutT) == 2)
          C[(size_t)(row + j) * ldc + col] = (OutT)f2bf(v);
        else
          C[(size_t)(row + j) * ldc + col] = v;
      }
    }
}

// ---------- flash attention (correctness-first: reg-staged LDS, padded, no swizzle) ----------
// grid (32 qtiles, 32 heads), 256 thr. QBLK=64 (16 rows/wave), KBLK=64.
__global__ __launch_bounds__(256) void fattn_kernel(const ushort_t* __restrict__ C1,
                                                    const ushort_t* __restrict__ VT,
                                                    ushort_t* __restrict__ AO) {
  __shared__ ushort_t Ks[64][136];    // 64 k-rows x 128 d (+8 pad, rows 16B-aligned)
  __shared__ ushort_t Vs[128][72];    // 128 d-rows x 64 k (+8 pad)
  __shared__ ushort_t Pl[4][16][72];  // per-wave P tile, +8 pad
  int qt = blockIdx.x, h = blockIdx.y;
  int hk = h >> 2;
  int q0 = qt * 64;
  int tid = threadIdx.x, w = tid >> 6, lane = tid & 63;
  int lr = lane & 15, lk = lane >> 4;

  // Q fragments in registers (A-operand: row=lr, d = kk*32 + lk*8 + j)
  bf16x8 qf[4];
  {
    const ushort_t* qrow = C1 + (size_t)(q0 + w * 16 + lr) * 6144 + h * 128;
#pragma unroll
    for (int kk = 0; kk < 4; kk++) qf[kk] = *(const bf16x8*)(qrow + kk * 32 + lk * 8);
  }
  f32x4 o[8] = {};
  float mrow[4], ssum[4];
#pragma unroll
  for (int j = 0; j < 4; j++) { mrow[j] = -1e30f; ssum[j] = 0.f; }
  const float scale = 0.08838834764831845f;  // 1/sqrt(128)

  for (int kt = 0; kt <= qt; kt++) {
    __syncthreads();  // prev iteration's reads done before restaging
    {
      const ushort_t* Kg = C1 + (size_t)(kt * 64) * 6144 + 4096 + hk * 128;
      const ushort_t* Vg = VT + (size_t)hk * 128 * 2048 + kt * 64;
#pragma unroll
      for (int it = 0; it < 4; it++) {
        int id = tid + it * 256;        // 0..1023
        {  // K tile: 64 rows x 16 chunks of 8
          int r = id >> 4, c = (id & 15) * 8;
          *(bf16x8*)&Ks[r][c] = *(const bf16x8*)(Kg + (size_t)r * 6144 + c);
        }
        {  // V tile: 128 rows x 8 chunks of 8
          int r = id >> 3, c = (id & 7) * 8;
          *(bf16x8*)&Vs[r][c] = *(const bf16x8*)(Vg + (size_t)r * 2048 + c);
        }
      }
    }
    __syncthreads();
    // S = Q K^T
    f32x4 s[4] = {};
#pragma unroll
    for (int kk = 0; kk < 4; kk++) {
#pragma unroll
      for (int n = 0; n < 4; n++) {
        bf16x8 kf = *(const bf16x8*)&Ks[n * 16 + lr][kk * 32 + lk * 8];
        s[n] = __builtin_amdgcn_mfma_f32_16x16x32_bf16(qf[kk], kf, s[n], 0, 0, 0);
      }
    }
    // scale + causal mask + online softmax
    bool diag = (kt == qt);
    float p[4][4], tm[4];
#pragma unroll
    for (int j = 0; j < 4; j++) tm[j] = -1e30f;
#pragma unroll
    for (int n = 0; n < 4; n++) {
      int k = kt * 64 + n * 16 + lr;
#pragma unroll
      for (int j = 0; j < 4; j++) {
        float v = s[n][j] * scale;
        if (diag) {
          int q = q0 + w * 16 + lk * 4 + j;
          if (k > q) v = -1e30f;
        }
        p[n][j] = v;
        tm[j] = fmaxf(tm[j], v);
      }
    }
#pragma unroll
    for (int off = 1; off < 16; off <<= 1)
#pragma unroll
      for (int j = 0; j < 4; j++) tm[j] = fmaxf(tm[j], __shfl_xor(tm[j], off, 64));
    float corr[4], mnew[4];
#pragma unroll
    for (int j = 0; j < 4; j++) {
      mnew[j] = fmaxf(mrow[j], tm[j]);
      corr[j] = __expf(mrow[j] - mnew[j]);
      mrow[j] = mnew[j];
    }
    float psum[4] = {0.f, 0.f, 0.f, 0.f};
#pragma unroll
    for (int n = 0; n < 4; n++)
#pragma unroll
      for (int j = 0; j < 4; j++) {
        float e = __expf(p[n][j] - mnew[j]);
        p[n][j] = e;
        psum[j] += e;
      }
#pragma unroll
    for (int off = 1; off < 16; off <<= 1)
#pragma unroll
      for (int j = 0; j < 4; j++) psum[j] += __shfl_xor(psum[j], off, 64);
#pragma unroll
    for (int j = 0; j < 4; j++) ssum[j] = ssum[j] * corr[j] + psum[j];
#pragma unroll
    for (int g = 0; g < 8; g++)
#pragma unroll
      for (int j = 0; j < 4; j++) o[g][j] *= corr[j];
    // P -> LDS (D-layout write, A-layout read)
#pragma unroll
    for (int n = 0; n < 4; n++)
#pragma unroll
      for (int j = 0; j < 4; j++) Pl[w][lk * 4 + j][n * 16 + lr] = f2bf(p[n][j]);
    __syncthreads();
    // O += P V
#pragma unroll
    for (int ks = 0; ks < 2; ks++) {
      bf16x8 pf = *(const bf16x8*)&Pl[w][lr][ks * 32 + lk * 8];
#pragma unroll
      for (int g = 0; g < 8; g++) {
        bf16x8 vf = *(const bf16x8*)&Vs[g * 16 + lr][ks * 32 + lk * 8];
        o[g] = __builtin_amdgcn_mfma_f32_16x16x32_bf16(pf, vf, o[g], 0, 0, 0);
      }
    }
  }
  // normalize + store
#pragma unroll
  for (int j = 0; j < 4; j++) {
    float inv = 1.0f / ssum[j];
    int q = q0 + w * 16 + lk * 4 + j;
    ushort_t* orow = AO + (size_t)q * 4096 + h * 128;
#pragma unroll
    for (int g = 0; g < 8; g++) orow[g * 16 + lr] = f2bf(o[g][j] * inv);
  }
}

// ---------- launch ----------
extern "C" void kernel_launch(void* const* d_in, const int* in_sizes, int n_in,
                              void* d_out, int out_size, void* d_ws, size_t ws_size,
                              hipStream_t stream) {
  (void)in_sizes; (void)n_in; (void)out_size; (void)ws_size;
  const float* x    = (const float*)d_in[0];
  const float* wq   = (const float*)d_in[1];
  const float* wk   = (const float*)d_in[2];
  const float* wv   = (const float*)d_in[3];
  const float* wo   = (const float*)d_in[4];
  const float* cosb = (const float*)d_in[5];
  const float* sinb = (const float*)d_in[6];

  char* ws = (char*)d_ws;
  ushort_t* xb  = (ushort_t*)(ws);                        // 16MB; reused as AO
  ushort_t* wT  = (ushort_t*)(ws + ((size_t)16 << 20));   // 48MB; reused as woT
  ushort_t* C1  = (ushort_t*)(ws + ((size_t)64 << 20));   // 24MB
  ushort_t* VT  = (ushort_t*)(ws + ((size_t)88 << 20));   // 4MB
  ushort_t* AO  = xb;
  ushort_t* woT = wT;

  // prep
  cvt_x_kernel<<<4096, 256, 0, stream>>>(x, xb);
  tr_cvt_kernel<<<dim3(64, 64), 256, 0, stream>>>(wq, wT, 4096, 4096);
  tr_cvt_kernel<<<dim3(16, 64), 256, 0, stream>>>(wk, wT + (size_t)4096 * 4096, 4096, 1024);
  tr_cvt_kernel<<<dim3(16, 64), 256, 0, stream>>>(wv, wT + (size_t)5120 * 4096, 4096, 1024);

  // QKV projection
  gemm128_kernel<ushort_t><<<dim3(48, 16), 256, 0, stream>>>(xb, wT, C1, 2048, 6144, 4096, 6144);
  // RoPE on Q,K
  rope_kernel<<<5120, 256, 0, stream>>>(C1, cosb, sinb);
  // V -> VT
  trv_kernel<<<dim3(16, 32), 256, 0, stream>>>(C1, VT);
  // wo -> woT (wT region is dead after gemm1; safe overlay in stream order)
  tr_cvt_kernel<<<dim3(64, 64), 256, 0, stream>>>(wo, woT, 4096, 4096);
  // attention
  fattn_kernel<<<dim3(32, 32), 256, 0, stream>>>(C1, VT, AO);
  // output projection -> FLOAT out (reference output dtype is float32!)
  gemm128_kernel<float><<<dim3(32, 16), 256, 0, stream>>>(AO, woT, (float*)d_out, 2048, 4096, 4096, 4096);
}

// Round 4
// 471.687 us; speedup vs baseline: 1.0346x; 1.0346x over previous
//
#include <hip/hip_runtime.h>
#include <stdint.h>

typedef unsigned short ushort_t;
typedef short bf16x8 __attribute__((ext_vector_type(8)));
typedef float f32x4 __attribute__((ext_vector_type(4)));
typedef float f32x4v __attribute__((ext_vector_type(4)));

// ---------- helpers ----------
__device__ __forceinline__ ushort_t f2bf(float f) {
  unsigned int u = __builtin_bit_cast(unsigned int, f);
  u += 0x7fffu + ((u >> 16) & 1u);
  return (ushort_t)(u >> 16);
}
__device__ __forceinline__ float bf2f(ushort_t h) {
  unsigned int u = ((unsigned int)h) << 16;
  return __builtin_bit_cast(float, u);
}
__device__ __forceinline__ void load_lds16(const void* g, void* l) {
  __builtin_amdgcn_global_load_lds(
      (const __attribute__((address_space(1))) void*)g,
      (__attribute__((address_space(3))) void*)l, 16, 0, 0);
}

// ---------- x fp32 -> bf16 ----------
__global__ __launch_bounds__(256) void cvt_x_kernel(const float* __restrict__ x,
                                                    ushort_t* __restrict__ xb) {
  int i = blockIdx.x * 256 + threadIdx.x;  // each thread: 8 elems
  const f32x4v* xv = (const f32x4v*)x;
  f32x4v a = xv[2 * i], b = xv[2 * i + 1];
  bf16x8 o;
  o[0] = (short)f2bf(a[0]); o[1] = (short)f2bf(a[1]);
  o[2] = (short)f2bf(a[2]); o[3] = (short)f2bf(a[3]);
  o[4] = (short)f2bf(b[0]); o[5] = (short)f2bf(b[1]);
  o[6] = (short)f2bf(b[2]); o[7] = (short)f2bf(b[3]);
  ((bf16x8*)xb)[i] = o;
}

// ---------- weight fp32 [R][C] -> bf16 transposed [C][R] ----------
__global__ __launch_bounds__(256) void tr_cvt_kernel(const float* __restrict__ src,
                                                     ushort_t* __restrict__ dst,
                                                     int R, int C) {
  __shared__ float tile[64][65];
  int r0 = blockIdx.y * 64, c0 = blockIdx.x * 64;
  int t = threadIdx.x;
#pragma unroll
  for (int i = 0; i < 16; i++) {
    int idx = t + i * 256;
    int r = idx >> 6, c = idx & 63;
    tile[r][c] = src[(size_t)(r0 + r) * C + c0 + c];
  }
  __syncthreads();
#pragma unroll
  for (int i = 0; i < 16; i++) {
    int idx = t + i * 256;
    int cr = idx >> 6, cc = idx & 63;
    dst[(size_t)(c0 + cr) * R + r0 + cc] = f2bf(tile[cc][cr]);
  }
}

// ---------- RoPE in-place on C1 (Q cols 0..4095, K cols 4096..5119) ----------
__global__ __launch_bounds__(256) void rope_kernel(ushort_t* __restrict__ C1,
                                                   const float* __restrict__ cosb,
                                                   const float* __restrict__ sinb) {
  int idx = blockIdx.x * 256 + threadIdx.x;  // 2048 * 640
  int s = idx / 640;
  int col0 = (idx % 640) * 8;
  int i0 = (col0 & 127) >> 1;
  ushort_t* p = C1 + (size_t)s * 6144 + col0;
  bf16x8 v = *(const bf16x8*)p;
  bf16x8 o;
  const float* cr = cosb + s * 64 + i0;
  const float* sr = sinb + s * 64 + i0;
#pragma unroll
  for (int j = 0; j < 4; j++) {
    float tr = bf2f((ushort_t)v[2 * j]);
    float ti = bf2f((ushort_t)v[2 * j + 1]);
    float c = cr[j], sn = sr[j];
    o[2 * j] = (short)f2bf(tr * c - ti * sn);
    o[2 * j + 1] = (short)f2bf(tr * sn + ti * c);
  }
  *(bf16x8*)p = o;
}

// ---------- V part of C1 -> VT [1024][2048] (row = hk*128+d, col = s) ----------
__global__ __launch_bounds__(256) void trv_kernel(const ushort_t* __restrict__ C1,
                                                  ushort_t* __restrict__ VT) {
  __shared__ ushort_t tile[64][65];
  int c0 = blockIdx.x * 64;  // within 1024
  int r0 = blockIdx.y * 64;  // within 2048
  int t = threadIdx.x;
#pragma unroll
  for (int i = 0; i < 16; i++) {
    int idx = t + i * 256;
    int r = idx >> 6, c = idx & 63;
    tile[r][c] = C1[(size_t)(r0 + r) * 6144 + 5120 + c0 + c];
  }
  __syncthreads();
#pragma unroll
  for (int i = 0; i < 16; i++) {
    int idx = t + i * 256;
    int cr = idx >> 6, cc = idx & 63;
    VT[(size_t)(c0 + cr) * 2048 + r0 + cc] = tile[cc][cr];
  }
}

// ---------- GEMM: C[M][ldc] = A[M][K] * BT[N][K]^T  (m97 structure) ----------
template <typename OutT>
__global__ __launch_bounds__(256) void gemm128_kernel(const ushort_t* __restrict__ A,
                                                      const ushort_t* __restrict__ BT,
                                                      OutT* __restrict__ C,
                                                      int M, int N, int K, int ldc) {
  __shared__ ushort_t As[128 * 32];
  __shared__ ushort_t Bs[128 * 32];
  int brow = blockIdx.y * 128, bcol = blockIdx.x * 128;
  int tid = threadIdx.x, w = tid >> 6, lane = tid & 63;
  int wr = w >> 1, wc = w & 1;
  int lr = lane & 15, lk = lane >> 4;
  f32x4 acc[4][4] = {};

  int srow = lane >> 2;
  int scol = (lane & 3) * 8;
  const ushort_t* Ab = A + (size_t)brow * K + scol;
  const ushort_t* Bb = BT + (size_t)bcol * K + scol;

  for (int kt = 0; kt < K; kt += 32) {
#pragma unroll
    for (int i = 0; i < 2; i++) {
      int seg = w * 2 + i;
      int row = seg * 16 + srow;
      load_lds16(Ab + (size_t)row * K + kt, (char*)As + seg * 1024);
      load_lds16(Bb + (size_t)row * K + kt, (char*)Bs + seg * 1024);
    }
    __syncthreads();
    bf16x8 af[4], bfr[4];
#pragma unroll
    for (int m = 0; m < 4; m++)
      af[m] = *(const bf16x8*)&As[(wr * 64 + m * 16 + lr) * 32 + lk * 8];
#pragma unroll
    for (int n = 0; n < 4; n++)
      bfr[n] = *(const bf16x8*)&Bs[(wc * 64 + n * 16 + lr) * 32 + lk * 8];
#pragma unroll
    for (int m = 0; m < 4; m++)
#pragma unroll
      for (int n = 0; n < 4; n++)
        acc[m][n] = __builtin_amdgcn_mfma_f32_16x16x32_bf16(af[m], bfr[n], acc[m][n], 0, 0, 0);
    __syncthreads();
  }
#pragma unroll
  for (int m = 0; m < 4; m++)
#pragma unroll
    for (int n = 0; n < 4; n++) {
      int row = brow + wr * 64 + m * 16 + lk * 4;
      int col = bcol + wc * 64 + n * 16 + lr;
#pragma unroll
      for (int j = 0; j < 4; j++) {
        float v = acc[m][n][j];
        if constexpr (sizeof(OutT) == 2)
          C[(size_t)(row + j) * ldc + col] = (OutT)f2bf(v);
        else
          C[(size_t)(row + j) * ldc + col] = v;
      }
    }
}

// ---------- flash attention, 2-phase pipelined ----------
// grid (16 qtiles x 32 heads), 512 thr (8 waves), QBLK=128 (16 rows/wave), KVBLK=64.
// K/V double-buffered in LDS via global_load_lds with XOR-swizzled global source
// (verified correct in round 1: identical output to padded reg-staged version).
__global__ __launch_bounds__(512) void fattn_kernel(const ushort_t* __restrict__ C1,
                                                    const ushort_t* __restrict__ VT,
                                                    ushort_t* __restrict__ AO) {
  __shared__ ushort_t Ks[2][64 * 128];  // 16KB x2
  __shared__ ushort_t Vs[2][128 * 64];  // 16KB x2
  __shared__ ushort_t Pl[8][16][72];    // per-wave P tile (+8 pad), 18KB
  const int qt = gridDim.x - 1 - blockIdx.x;  // longest blocks first
  const int h = blockIdx.y, hk = h >> 2;
  const int q0 = qt * 128;
  const int tid = threadIdx.x, w = tid >> 6, lane = tid & 63;
  const int lr = lane & 15, lk = lane >> 4;

  const char* Kg0 = (const char*)(C1 + 4096 + (size_t)hk * 128);  // row stride 12288B
  const char* Vg0 = (const char*)(VT + (size_t)hk * 128 * 2048);  // row stride 4096B

  // stage K/V tile kt into buffer buf. LDS dest linear (wave base + lane*16);
  // global source pre-XOR'd so LDS chunk c of row r holds global chunk c^(r&7).
  auto stage = [&](int kt, int buf) {
#pragma unroll
    for (int i = 0; i < 2; i++) {
      int seg = w * 2 + i;  // 16 segments of 1024B, 2 per wave
      {
        int row = seg * 4 + (lane >> 4);  // K: 4 rows (256B) per segment
        int srcb = ((lane & 15) << 4) ^ ((row & 7) << 4);
        load_lds16(Kg0 + (size_t)(kt * 64 + row) * 12288 + srcb,
                   (char*)&Ks[buf][0] + seg * 1024);
      }
      {
        int rv = seg * 8 + (lane >> 3);  // V: 8 rows (128B) per segment
        int srcv = ((lane & 7) << 4) ^ ((rv & 7) << 4);
        load_lds16(Vg0 + (size_t)rv * 4096 + (size_t)kt * 128 + srcv,
                   (char*)&Vs[buf][0] + seg * 1024);
      }
    }
  };

  // Q fragments in registers (A-operand: row=lr, d = kk*32 + lk*8 + j)
  bf16x8 qf[4];
  {
    const ushort_t* qrow = C1 + (size_t)(q0 + w * 16 + lr) * 6144 + h * 128;
#pragma unroll
    for (int kk = 0; kk < 4; kk++) qf[kk] = *(const bf16x8*)(qrow + kk * 32 + lk * 8);
  }
  f32x4 o[8] = {};
  float mrow[4], ssum[4];
#pragma unroll
  for (int j = 0; j < 4; j++) { mrow[j] = -1e30f; ssum[j] = 0.f; }
  const float scale = 0.08838834764831845f;  // 1/sqrt(128)

  const int ktmax = 2 * qt + 1;
  stage(0, 0);
  __syncthreads();  // compiler drains vmcnt(0) here -> buf0 ready

  for (int kt = 0; kt <= ktmax; kt++) {
    const int cur = kt & 1;
    if (kt < ktmax) stage(kt + 1, cur ^ 1);  // async prefetch; latency hides under compute

    if (kt * 64 <= q0 + w * 16 + 15) {  // wave has unmasked work in this K-tile
      const char* Kb = (const char*)&Ks[cur][0];
      const char* Vb = (const char*)&Vs[cur][0];
      // S = Q K^T
      f32x4 s[4] = {};
#pragma unroll
      for (int kk = 0; kk < 4; kk++) {
#pragma unroll
        for (int n = 0; n < 4; n++) {
          int row = n * 16 + lr;
          bf16x8 kf = *(const bf16x8*)(Kb + row * 256 +
                                       ((lk * 16 + kk * 64) ^ ((row & 7) << 4)));
          s[n] = __builtin_amdgcn_mfma_f32_16x16x32_bf16(qf[kk], kf, s[n], 0, 0, 0);
        }
      }
      // scale + causal mask + online softmax
      const bool needmask = (kt * 64 + 63 > q0 + w * 16);
      float p[4][4], tm[4];
#pragma unroll
      for (int j = 0; j < 4; j++) tm[j] = -1e30f;
#pragma unroll
      for (int n = 0; n < 4; n++) {
        int k = kt * 64 + n * 16 + lr;
#pragma unroll
        for (int j = 0; j < 4; j++) {
          float v = s[n][j] * scale;
          if (needmask) {
            int q = q0 + w * 16 + lk * 4 + j;
            if (k > q) v = -1e30f;
          }
          p[n][j] = v;
          tm[j] = fmaxf(tm[j], v);
        }
      }
#pragma unroll
      for (int off = 1; off < 16; off <<= 1)
#pragma unroll
        for (int j = 0; j < 4; j++) tm[j] = fmaxf(tm[j], __shfl_xor(tm[j], off, 64));
      float corr[4], mnew[4];
#pragma unroll
      for (int j = 0; j < 4; j++) {
        mnew[j] = fmaxf(mrow[j], tm[j]);
        corr[j] = __expf(mrow[j] - mnew[j]);
        mrow[j] = mnew[j];
      }
      float psum[4] = {0.f, 0.f, 0.f, 0.f};
#pragma unroll
      for (int n = 0; n < 4; n++)
#pragma unroll
        for (int j = 0; j < 4; j++) {
          float e = __expf(p[n][j] - mnew[j]);
          p[n][j] = e;
          psum[j] += e;
        }
#pragma unroll
      for (int off = 1; off < 16; off <<= 1)
#pragma unroll
        for (int j = 0; j < 4; j++) psum[j] += __shfl_xor(psum[j], off, 64);
#pragma unroll
      for (int j = 0; j < 4; j++) ssum[j] = ssum[j] * corr[j] + psum[j];
#pragma unroll
      for (int g = 0; g < 8; g++)
#pragma unroll
        for (int j = 0; j < 4; j++) o[g][j] *= corr[j];
      // P -> per-wave LDS (D-layout write, A-layout read) — no block barrier needed,
      // only this wave touches Pl[w]; order via lgkmcnt drain (+compile-time "memory").
#pragma unroll
      for (int n = 0; n < 4; n++)
#pragma unroll
        for (int j = 0; j < 4; j++) Pl[w][lk * 4 + j][n * 16 + lr] = f2bf(p[n][j]);
      asm volatile("s_waitcnt lgkmcnt(0)" ::: "memory");
      // O += P V
#pragma unroll
      for (int ks = 0; ks < 2; ks++) {
        bf16x8 pf = *(const bf16x8*)&Pl[w][lr][ks * 32 + lk * 8];
#pragma unroll
        for (int g = 0; g < 8; g++) {
          int d = g * 16 + lr;
          bf16x8 vf = *(const bf16x8*)(Vb + d * 128 +
                                       ((lk * 16 + ks * 64) ^ ((d & 7) << 4)));
          o[g] = __builtin_amdgcn_mfma_f32_16x16x32_bf16(pf, vf, o[g], 0, 0, 0);
        }
      }
    }
    __syncthreads();  // drains vmcnt -> next buf staged; all waves done reading cur
  }
  // normalize + store
#pragma unroll
  for (int j = 0; j < 4; j++) {
    float inv = 1.0f / ssum[j];
    int q = q0 + w * 16 + lk * 4 + j;
    ushort_t* orow = AO + (size_t)q * 4096 + h * 128;
#pragma unroll
    for (int g = 0; g < 8; g++) orow[g * 16 + lr] = f2bf(o[g][j] * inv);
  }
}

// ---------- launch ----------
extern "C" void kernel_launch(void* const* d_in, const int* in_sizes, int n_in,
                              void* d_out, int out_size, void* d_ws, size_t ws_size,
                              hipStream_t stream) {
  (void)in_sizes; (void)n_in; (void)out_size; (void)ws_size;
  const float* x    = (const float*)d_in[0];
  const float* wq   = (const float*)d_in[1];
  const float* wk   = (const float*)d_in[2];
  const float* wv   = (const float*)d_in[3];
  const float* wo   = (const float*)d_in[4];
  const float* cosb = (const float*)d_in[5];
  const float* sinb = (const float*)d_in[6];

  char* ws = (char*)d_ws;
  ushort_t* xb  = (ushort_t*)(ws);                        // 16MB; reused as AO
  ushort_t* wT  = (ushort_t*)(ws + ((size_t)16 << 20));   // 48MB; reused as woT
  ushort_t* C1  = (ushort_t*)(ws + ((size_t)64 << 20));   // 24MB
  ushort_t* VT  = (ushort_t*)(ws + ((size_t)88 << 20));   // 4MB
  ushort_t* AO  = xb;
  ushort_t* woT = wT;

  // prep
  cvt_x_kernel<<<4096, 256, 0, stream>>>(x, xb);
  tr_cvt_kernel<<<dim3(64, 64), 256, 0, stream>>>(wq, wT, 4096, 4096);
  tr_cvt_kernel<<<dim3(16, 64), 256, 0, stream>>>(wk, wT + (size_t)4096 * 4096, 4096, 1024);
  tr_cvt_kernel<<<dim3(16, 64), 256, 0, stream>>>(wv, wT + (size_t)5120 * 4096, 4096, 1024);

  // QKV projection
  gemm128_kernel<ushort_t><<<dim3(48, 16), 256, 0, stream>>>(xb, wT, C1, 2048, 6144, 4096, 6144);
  // RoPE on Q,K
  rope_kernel<<<5120, 256, 0, stream>>>(C1, cosb, sinb);
  // V -> VT
  trv_kernel<<<dim3(16, 32), 256, 0, stream>>>(C1, VT);
  // wo -> woT (wT region is dead after gemm1; safe overlay in stream order)
  tr_cvt_kernel<<<dim3(64, 64), 256, 0, stream>>>(wo, woT, 4096, 4096);
  // attention (8 waves, QBLK=128, double-buffered K/V)
  fattn_kernel<<<dim3(16, 32), 512, 0, stream>>>(C1, VT, AO);
  // output projection -> FLOAT out
  gemm128_kernel<float><<<dim3(32, 16), 256, 0, stream>>>(AO, woT, (float*)d_out, 2048, 4096, 4096, 4096);
}